// Round 9
// baseline (146.176 us; speedup 1.0000x reference)
//
#include <hip/hip_runtime.h>

// Problem constants
#define T_LEN 4096
#define N_WIN 3969          // T - L + 1
#define K_SH  128
#define L_SH  128
#define B_SZ  256

#define SSTR  136           // S row stride (bf16 elems), 272 B
// per-half x copy stride (bf16 elems): 4496 B; 4496/4 = 1124 dwords ≡ 4 (mod 32)
// -> 8 copy bases land on distinct banks. Capacity: lower half needs 2175 elems
// (x[0..2174] for windows n<=2047), upper needs 2048; 2248 covers both + pad.
#define XSTRH 2248

typedef __attribute__((ext_vector_type(8))) __bf16 bf16x8;
typedef __attribute__((ext_vector_type(4))) float f32x4;
typedef _Float16 h2 __attribute__((ext_vector_type(2)));   // packed half pair

__device__ __forceinline__ unsigned short f2bf(float f) {
    union { float f; unsigned int u; } c; c.f = f;
    unsigned int u = c.u + 0x7fff + ((c.u >> 16) & 1u);
    return (unsigned short)(u >> 16);
}
__device__ __forceinline__ unsigned int pack2(unsigned short lo, unsigned short hi) {
    return (unsigned int)lo | ((unsigned int)hi << 16);
}

// ---- packed-f16 selection primitives (each op handles BOTH packed lists) ----
__device__ __forceinline__ h2 max2(h2 a, h2 b) { return __builtin_elementwise_max(a, b); }
__device__ __forceinline__ h2 min2(h2 a, h2 b) { return __builtin_elementwise_min(a, b); }
__device__ __forceinline__ h2 cvt2(float lo, float hi) {   // lo -> elem0, hi -> elem1
    return __builtin_bit_cast(h2, __builtin_amdgcn_cvt_pkrtz(lo, hi));
}
__device__ __forceinline__ void ce2(h2& hi, h2& lo) {
    const h2 m = max2(hi, lo);
    lo = min2(hi, lo);
    hi = m;
}
__device__ __forceinline__ void sort4_2(h2& a, h2& b, h2& c, h2& d) {
    ce2(a, b); ce2(c, d); ce2(a, c); ce2(b, d); ce2(b, c);
}
// top-5 of two descending sorted 4-lists (odd-even merge, 8 comparators)
__device__ __forceinline__ void merge44_top5_2(h2 a0, h2 a1, h2 a2, h2 a3,
                                               h2 b0, h2 b1, h2 b2, h2 b3,
                                               h2& r0, h2& r1, h2& r2, h2& r3, h2& r4) {
    ce2(a0, b0); ce2(a2, b2); ce2(b0, a2);
    ce2(a1, b1); ce2(a3, b3); ce2(b1, a3);
    r0 = a0;
    r1 = a1; r2 = b0; ce2(r1, r2);
    r3 = b1; r4 = a2; ce2(r3, r4);
}
// r = top-5 of union of two descending sorted 5-lists (c_k = max_{i+j=k} min(a_i,b_j))
__device__ __forceinline__ void merge55_2(h2& r0, h2& r1, h2& r2, h2& r3, h2& r4,
                                          h2 s0, h2 s1, h2 s2, h2 s3, h2 s4) {
    const h2 m00 = min2(r0, s0);
    const h2 m10 = min2(r1, s0), m01 = min2(r0, s1);
    const h2 m20 = min2(r2, s0), m11 = min2(r1, s1), m02 = min2(r0, s2);
    const h2 m30 = min2(r3, s0), m21 = min2(r2, s1), m12 = min2(r1, s2), m03 = min2(r0, s3);
    const h2 n0 = max2(r0, s0);
    const h2 n1 = max2(max2(r1, s1), m00);
    const h2 n2 = max2(max2(r2, s2), max2(m10, m01));
    const h2 n3 = max2(max2(max2(r3, s3), m20), max2(m11, m02));
    const h2 n4 = max2(max2(max2(r4, s4), max2(m30, m03)), max2(m21, m12));
    r0 = n0; r1 = n1; r2 = n2; r3 = n3; r4 = n4;
}
// packed single-value insert (epilogue only)
__device__ __forceinline__ void insert1_2(h2 v, h2* rt) {
    h2 b = max2(rt[4], v); h2 m;
    m = max2(rt[3], b);     b     = min2(rt[3], b);     rt[3] = m;
    m = max2(rt[2], rt[3]); rt[3] = min2(rt[2], rt[3]); rt[2] = m;
    m = max2(rt[1], rt[2]); rt[2] = min2(rt[1], rt[2]); rt[1] = m;
    m = max2(rt[0], rt[1]); rt[1] = min2(rt[0], rt[1]); rt[0] = m;
    rt[4] = b;
}
// per-tile: fold 32 acc values (16 per list) into packed running top-5
__device__ __forceinline__ void select32(const f32x4* acc0, const f32x4* acc1, h2* rt) {
    h2 p[16];
    #pragma unroll
    for (int m = 0; m < 4; ++m)
        #pragma unroll
        for (int i = 0; i < 4; ++i)
            p[4 * m + i] = cvt2(acc0[m][i], acc1[m][i]);
    sort4_2(p[0], p[1], p[2],  p[3]);
    sort4_2(p[4], p[5], p[6],  p[7]);
    sort4_2(p[8], p[9], p[10], p[11]);
    sort4_2(p[12], p[13], p[14], p[15]);
    h2 u0, u1, u2, u3, u4, v0, v1, v2, v3, v4;
    merge44_top5_2(p[0], p[1], p[2],  p[3],  p[4],  p[5],  p[6],  p[7],  u0, u1, u2, u3, u4);
    merge44_top5_2(p[8], p[9], p[10], p[11], p[12], p[13], p[14], p[15], v0, v1, v2, v3, v4);
    merge55_2(u0, u1, u2, u3, u4, v0, v1, v2, v3, v4);
    merge55_2(rt[0], rt[1], rt[2], rt[3], rt[4], u0, u1, u2, u3, u4);
}

// Kernel 1: grid = 2*B (512 blocks, 2/CU), 1024 threads (16 waves, 8/SIMD).
// Block (b, half): half's n-range is [half*2048, half*2048 + {2048|1921}).
// Wave w: g = w>>3 local-tile parity; mh = (w>>2)&1 mt-half; wp = w&3 kt pair.
__global__ __launch_bounds__(1024, 8)
void shapelet_half_kernel(const float* __restrict__ x,
                          const float* __restrict__ s,
                          unsigned int* __restrict__ part) {
    __shared__ __align__(16) unsigned short ldsS[K_SH * SSTR];   // 34816 B
    __shared__ __align__(16) unsigned short ldsX[8 * XSTRH];     // 35968 B

    const int t    = threadIdx.x;
    const int lane = t & 63;
    const int w    = t >> 6;
    const int r    = lane & 15;
    const int q    = lane >> 4;
    const int c7   = lane & 7;
    const int ub   = (lane >> 3) & 1;
    const int g    = w >> 3;          // local-tile parity group
    const int w7   = w & 7;
    const int mh   = w7 >> 2;
    const int wp   = w7 & 3;
    const int mtb  = 4 * mh;
    const int half = blockIdx.x & 1;
    const int b    = blockIdx.x >> 1;

    // ---- stage centered S as bf16: 8 threads per row k, 16 elems each ----
    {
        const int k = t >> 3, e8 = t & 7;
        const float4* srow = (const float4*)(s + k * L_SH + e8 * 16);
        float4 v[4];
        float sum = 0.0f;
        #pragma unroll
        for (int j = 0; j < 4; ++j) {
            v[j] = srow[j];
            sum += (v[j].x + v[j].y) + (v[j].z + v[j].w);
        }
        sum += __shfl_xor(sum, 1);
        sum += __shfl_xor(sum, 2);
        sum += __shfl_xor(sum, 4);
        const float mean = sum * (1.0f / 128.0f);
        uint4* dst = (uint4*)((char*)ldsS + k * (SSTR * 2) + e8 * 32);
        #pragma unroll
        for (int j = 0; j < 2; ++j) {
            uint4 o;
            o.x = pack2(f2bf(v[2*j].x - mean),   f2bf(v[2*j].y - mean));
            o.y = pack2(f2bf(v[2*j].z - mean),   f2bf(v[2*j].w - mean));
            o.z = pack2(f2bf(v[2*j+1].x - mean), f2bf(v[2*j+1].y - mean));
            o.w = pack2(f2bf(v[2*j+1].z - mean), f2bf(v[2*j+1].w - mean));
            dst[j] = o;
        }
        if (e8 == 7) *(uint4*)((char*)ldsS + k * (SSTR * 2) + 256) = make_uint4(0,0,0,0);
    }

    // ---- stage this half's x slice as 8 shifted bf16 copies ----
    {
        const float* __restrict__ xb = x + (size_t)b * T_LEN + half * 2048;
        const int navail = half ? 2048 : 2175;     // elems available in this slice
        const int a = t & 7;
        for (int i = (t >> 3); i < XSTRH / 8; i += 128) {   // 281 chunks
            const int p0 = 8 * i;
            float xv[16];
            if (p0 + 16 <= 2048) {
                const float4* sp = (const float4*)(xb + p0);
                #pragma unroll
                for (int j = 0; j < 4; ++j) *(float4*)(xv + 4 * j) = sp[j];
            } else {
                #pragma unroll
                for (int j = 0; j < 16; ++j) {
                    const int gi = p0 + j;
                    xv[j] = (gi < navail) ? xb[gi] : 0.0f;
                }
            }
            unsigned short bv[16];
            #pragma unroll
            for (int j = 0; j < 16; ++j) bv[j] = f2bf(xv[j]);
            uint4 o;
            o.x = pack2(bv[a],     bv[a + 1]);
            o.y = pack2(bv[a + 2], bv[a + 3]);
            o.z = pack2(bv[a + 4], bv[a + 5]);
            o.w = pack2(bv[a + 6], bv[a + 7]);
            *(uint4*)((char*)ldsX + a * (XSTRH * 2) + 2 * p0) = o;   // copy a elem p = x[p+a]
        }
    }
    __syncthreads();

    // ---- hoist B fragments (shapelets) to registers: 2 kts x 4 K-chunks ----
    bf16x8 bfr[2][4];
    #pragma unroll
    for (int kk = 0; kk < 2; ++kk)
        #pragma unroll
        for (int c = 0; c < 4; ++c)
            bfr[kk][c] = __builtin_bit_cast(bf16x8, *(const uint4*)(
                (const char*)ldsS + ((2 * wp + kk) * 16 + r) * (SSTR * 2) + 64 * c + 16 * q));

    // packed running top-5: elem0 -> ks = 32*wp + r, elem1 -> ks = 32*wp + 16 + r
    h2 rt[5];
    #pragma unroll
    for (int i = 0; i < 5; ++i) rt[i] = __builtin_bit_cast(h2, 0xFC00FC00u);  // (-inf,-inf)

    // group g starts at local tile g; advances 2 tiles (512 B) per step
    const char* xp = (const char*)ldsX + c7 * (XSTRH * 2) + 16 * q + 16 * ub + 32 * mtb
                   + g * 256;

#define TILE_STEP                                                               \
    {                                                                           \
        bf16x8 afr[10];                                                         \
        _Pragma("unroll")                                                       \
        for (int j = 0; j < 10; ++j)                                            \
            afr[j] = __builtin_bit_cast(bf16x8, *(const uint4*)(xp + 32 * j));  \
        xp += 512;                                                              \
        f32x4 acc0[4], acc1[4];                                                 \
        _Pragma("unroll")                                                       \
        for (int m = 0; m < 4; ++m) {                                           \
            acc0[m] = (f32x4){0.f, 0.f, 0.f, 0.f};                              \
            acc1[m] = (f32x4){0.f, 0.f, 0.f, 0.f};                              \
        }                                                                       \
        _Pragma("unroll")                                                       \
        for (int c = 0; c < 4; ++c) {                                           \
            _Pragma("unroll")                                                   \
            for (int m = 0; m < 4; ++m) {                                       \
                acc0[m] = __builtin_amdgcn_mfma_f32_16x16x32_bf16(afr[m + 2*c], bfr[0][c], acc0[m], 0, 0, 0); \
                acc1[m] = __builtin_amdgcn_mfma_f32_16x16x32_bf16(afr[m + 2*c], bfr[1][c], acc1[m], 0, 0, 0); \
            }                                                                   \
        }                                                                       \
        select32(acc0, acc1, rt);                                               \
    }

    // local tiles: half0 g0: {0,2,..,14}, g1: {1,..,15}; half1 g0: {0,..,14},
    // g1: {1,..,13} (lt=15 would start n=3968 -> handled as boundary row).
    for (int st = 0; st < 7; ++st) { TILE_STEP }
    if (!(half & g)) { TILE_STEP }
#undef TILE_STEP

    // ---- boundary row n = 3968 (upper half, local elem 1920) ----
    if (half == 1 && g == 1 && mh == 0) {
        f32x4 e0 = (f32x4){0.f, 0.f, 0.f, 0.f};
        f32x4 e1 = (f32x4){0.f, 0.f, 0.f, 0.f};
        const char* eb = (const char*)ldsX + c7 * (XSTRH * 2) + 3840 + 16 * q + 16 * ub;
        #pragma unroll
        for (int c = 0; c < 4; ++c) {
            const bf16x8 af = __builtin_bit_cast(bf16x8, *(const uint4*)(eb + 64 * c));
            e0 = __builtin_amdgcn_mfma_f32_16x16x32_bf16(af, bfr[0][c], e0, 0, 0, 0);
            e1 = __builtin_amdgcn_mfma_f32_16x16x32_bf16(af, bfr[1][c], e1, 0, 0, 0);
        }
        if (q == 0) insert1_2(cvt2(e0[0], e1[0]), rt);   // n = 3968 for both lists
    }

    // ---- butterfly merge across quads (snapshot BEFORE merging) ----
    #pragma unroll
    for (int mask = 16; mask <= 32; mask <<= 1) {
        h2 sv[5];
        #pragma unroll
        for (int i = 0; i < 5; ++i)
            sv[i] = __builtin_bit_cast(h2, __shfl_xor(__builtin_bit_cast(int, rt[i]), mask));
        merge55_2(rt[0], rt[1], rt[2], rt[3], rt[4], sv[0], sv[1], sv[2], sv[3], sv[4]);
    }

    // ---- cross-(g, mh) merge via LDS: 3 writer combos, reader (g=0, mh=0) ----
    __syncthreads();   // bfr-hoist reads of ldsS long done; reuse as scratch
    unsigned int* pbuf = (unsigned int*)ldsS;   // [region][wp*16 + r][5]
    if ((g != 0 || mh != 0) && q == 0) {
        const int reg = (g * 2 + mh) - 1;       // 0..2
        unsigned int* p = pbuf + ((reg * 64) + wp * 16 + r) * 5;
        #pragma unroll
        for (int i = 0; i < 5; ++i) p[i] = __builtin_bit_cast(unsigned int, rt[i]);
    }
    __syncthreads();
    if (g == 0 && mh == 0 && q == 0) {
        #pragma unroll
        for (int reg = 0; reg < 3; ++reg) {
            const unsigned int* p = pbuf + ((reg * 64) + wp * 16 + r) * 5;
            h2 sv[5];
            #pragma unroll
            for (int i = 0; i < 5; ++i) sv[i] = __builtin_bit_cast(h2, p[i]);
            merge55_2(rt[0], rt[1], rt[2], rt[3], rt[4], sv[0], sv[1], sv[2], sv[3], sv[4]);
        }
        // packed partials: part[(half*5 + j)*16384 + b*64 + cid]
        const int cid = wp * 16 + r;
        unsigned int* p = part + (size_t)(half * 5) * 16384 + b * 64 + cid;
        #pragma unroll
        for (int j = 0; j < 5; ++j)
            p[(size_t)j * 16384] = __builtin_bit_cast(unsigned int, rt[j]);
    }
}

// Kernel 2: merge the two half partials per (b, cid), emit features for 2 ks each
__global__ void merge_half_kernel(const unsigned int* __restrict__ part,
                                  float* __restrict__ out) {
    const int gid = blockIdx.x * 256 + threadIdx.x;   // 0 .. 16383
    const int b   = gid >> 6;
    const int cid = gid & 63;

    h2 rt[5], sv[5];
    #pragma unroll
    for (int j = 0; j < 5; ++j) rt[j] = __builtin_bit_cast(h2, part[(size_t)j * 16384 + gid]);
    #pragma unroll
    for (int j = 0; j < 5; ++j) sv[j] = __builtin_bit_cast(h2, part[(size_t)(5 + j) * 16384 + gid]);
    merge55_2(rt[0], rt[1], rt[2], rt[3], rt[4], sv[0], sv[1], sv[2], sv[3], sv[4]);

    const float A0 = (float)rt[0][0], A1 = (float)rt[1][0], A2 = (float)rt[2][0],
                A3 = (float)rt[3][0], A4 = (float)rt[4][0];
    const float B0 = (float)rt[0][1], B1 = (float)rt[1][1], B2 = (float)rt[2][1],
                B3 = (float)rt[3][1], B4 = (float)rt[4][1];
    float* ob = out + (size_t)b * (4 * K_SH);
    const int ksA = 32 * (cid >> 4) + (cid & 15), ksB = ksA + 16;
    const float mA = (((A0 + A1) + (A2 + A3)) + A4) * 0.2f;
    const float mB = (((B0 + B1) + (B2 + B3)) + B4) * 0.2f;
    ob[ksA]           = A0;
    ob[K_SH + ksA]    = mA;
    ob[2*K_SH + ksA]  = A1;
    ob[3*K_SH + ksA]  = fmaxf(A0 - A1, 0.0f);
    ob[ksB]           = B0;
    ob[K_SH + ksB]    = mB;
    ob[2*K_SH + ksB]  = B1;
    ob[3*K_SH + ksB]  = fmaxf(B0 - B1, 0.0f);
}

extern "C" void kernel_launch(void* const* d_in, const int* in_sizes, int n_in,
                              void* d_out, int out_size, void* d_ws, size_t ws_size,
                              hipStream_t stream) {
    const float* x = (const float*)d_in[0];        // (256, 4096) fp32
    const float* s = (const float*)d_in[1];        // (128, 128)  fp32
    float* out = (float*)d_out;                    // (256, 512)  fp32
    unsigned int* part = (unsigned int*)d_ws;      // 10 * 16384 u32 = 640 KB

    shapelet_half_kernel<<<2 * B_SZ, 1024, 0, stream>>>(x, s, part);
    merge_half_kernel<<<64, 256, 0, stream>>>(part, out);
}

// Round 10
// 97.401 us; speedup vs baseline: 1.5008x; 1.5008x over previous
//
#include <hip/hip_runtime.h>

// Problem constants
#define T_LEN 4096
#define N_WIN 3969          // T - L + 1
#define K_SH  128
#define L_SH  128
#define B_SZ  256

#define SSTR  136           // S row stride (bf16 elems), 272 B
// per-half x copy stride (bf16 elems): 4496 B; 4496/4 = 1124 dwords ≡ 4 (mod 32)
// -> 8 copy bases land on distinct banks. Capacity: lower half needs 2175 elems
// (x[0..2174] for windows n<=2047), upper needs 2048; 2248 covers both + pad.
#define XSTRH 2248

typedef __attribute__((ext_vector_type(8))) __bf16 bf16x8;
typedef __attribute__((ext_vector_type(4))) float f32x4;
typedef _Float16 h2 __attribute__((ext_vector_type(2)));   // packed half pair

__device__ __forceinline__ unsigned short f2bf(float f) {
    union { float f; unsigned int u; } c; c.f = f;
    unsigned int u = c.u + 0x7fff + ((c.u >> 16) & 1u);
    return (unsigned short)(u >> 16);
}
__device__ __forceinline__ unsigned int pack2(unsigned short lo, unsigned short hi) {
    return (unsigned int)lo | ((unsigned int)hi << 16);
}

// ---- packed-f16 selection primitives (each op handles BOTH packed lists) ----
__device__ __forceinline__ h2 max2(h2 a, h2 b) { return __builtin_elementwise_max(a, b); }
__device__ __forceinline__ h2 min2(h2 a, h2 b) { return __builtin_elementwise_min(a, b); }
__device__ __forceinline__ h2 cvt2(float lo, float hi) {   // lo -> elem0, hi -> elem1
    return __builtin_bit_cast(h2, __builtin_amdgcn_cvt_pkrtz(lo, hi));
}
__device__ __forceinline__ void ce2(h2& hi, h2& lo) {
    const h2 m = max2(hi, lo);
    lo = min2(hi, lo);
    hi = m;
}
__device__ __forceinline__ void sort4_2(h2& a, h2& b, h2& c, h2& d) {
    ce2(a, b); ce2(c, d); ce2(a, c); ce2(b, d); ce2(b, c);
}
// top-5 of two descending sorted 4-lists (odd-even merge, 8 comparators)
__device__ __forceinline__ void merge44_top5_2(h2 a0, h2 a1, h2 a2, h2 a3,
                                               h2 b0, h2 b1, h2 b2, h2 b3,
                                               h2& r0, h2& r1, h2& r2, h2& r3, h2& r4) {
    ce2(a0, b0); ce2(a2, b2); ce2(b0, a2);
    ce2(a1, b1); ce2(a3, b3); ce2(b1, a3);
    r0 = a0;
    r1 = a1; r2 = b0; ce2(r1, r2);
    r3 = b1; r4 = a2; ce2(r3, r4);
}
// r = top-5 of union of two descending sorted 5-lists (c_k = max_{i+j=k} min(a_i,b_j))
__device__ __forceinline__ void merge55_2(h2& r0, h2& r1, h2& r2, h2& r3, h2& r4,
                                          h2 s0, h2 s1, h2 s2, h2 s3, h2 s4) {
    const h2 m00 = min2(r0, s0);
    const h2 m10 = min2(r1, s0), m01 = min2(r0, s1);
    const h2 m20 = min2(r2, s0), m11 = min2(r1, s1), m02 = min2(r0, s2);
    const h2 m30 = min2(r3, s0), m21 = min2(r2, s1), m12 = min2(r1, s2), m03 = min2(r0, s3);
    const h2 n0 = max2(r0, s0);
    const h2 n1 = max2(max2(r1, s1), m00);
    const h2 n2 = max2(max2(r2, s2), max2(m10, m01));
    const h2 n3 = max2(max2(max2(r3, s3), m20), max2(m11, m02));
    const h2 n4 = max2(max2(max2(r4, s4), max2(m30, m03)), max2(m21, m12));
    r0 = n0; r1 = n1; r2 = n2; r3 = n3; r4 = n4;
}
// packed single-value insert (epilogue only)
__device__ __forceinline__ void insert1_2(h2 v, h2* rt) {
    h2 b = max2(rt[4], v); h2 m;
    m = max2(rt[3], b);     b     = min2(rt[3], b);     rt[3] = m;
    m = max2(rt[2], rt[3]); rt[3] = min2(rt[2], rt[3]); rt[2] = m;
    m = max2(rt[1], rt[2]); rt[2] = min2(rt[1], rt[2]); rt[1] = m;
    m = max2(rt[0], rt[1]); rt[1] = min2(rt[0], rt[1]); rt[0] = m;
    rt[4] = b;
}
// per-tile: fold 32 acc values (16 per list) into packed running top-5
__device__ __forceinline__ void select32(const f32x4* acc0, const f32x4* acc1, h2* rt) {
    h2 p[16];
    #pragma unroll
    for (int m = 0; m < 4; ++m)
        #pragma unroll
        for (int i = 0; i < 4; ++i)
            p[4 * m + i] = cvt2(acc0[m][i], acc1[m][i]);
    sort4_2(p[0], p[1], p[2],  p[3]);
    sort4_2(p[4], p[5], p[6],  p[7]);
    sort4_2(p[8], p[9], p[10], p[11]);
    sort4_2(p[12], p[13], p[14], p[15]);
    h2 u0, u1, u2, u3, u4, v0, v1, v2, v3, v4;
    merge44_top5_2(p[0], p[1], p[2],  p[3],  p[4],  p[5],  p[6],  p[7],  u0, u1, u2, u3, u4);
    merge44_top5_2(p[8], p[9], p[10], p[11], p[12], p[13], p[14], p[15], v0, v1, v2, v3, v4);
    merge55_2(u0, u1, u2, u3, u4, v0, v1, v2, v3, v4);
    merge55_2(rt[0], rt[1], rt[2], rt[3], rt[4], u0, u1, u2, u3, u4);
}

// Kernel 1: grid = 2*B (512 blocks, 2/CU by HW occupancy), 1024 threads (16 waves).
// NOTE: no min-waves launch-bound — R9's (1024,8) forced a catastrophic spill
// (VGPR 56->32, 140 MB scratch traffic). R8 measured 56 VGPR for this body,
// under the 64 ceiling needed for 2 blocks/CU; let the allocator repeat that.
// Block (b, half): half's n-range is [half*2048, half*2048 + {2048|1921}).
// Wave w: g = w>>3 local-tile parity; mh = (w>>2)&1 mt-half; wp = w&3 kt pair.
__global__ __launch_bounds__(1024)
void shapelet_half_kernel(const float* __restrict__ x,
                          const float* __restrict__ s,
                          unsigned int* __restrict__ part) {
    __shared__ __align__(16) unsigned short ldsS[K_SH * SSTR];   // 34816 B
    __shared__ __align__(16) unsigned short ldsX[8 * XSTRH];     // 35968 B

    const int t    = threadIdx.x;
    const int lane = t & 63;
    const int w    = t >> 6;
    const int r    = lane & 15;
    const int q    = lane >> 4;
    const int c7   = lane & 7;
    const int ub   = (lane >> 3) & 1;
    const int g    = w >> 3;          // local-tile parity group
    const int w7   = w & 7;
    const int mh   = w7 >> 2;
    const int wp   = w7 & 3;
    const int mtb  = 4 * mh;
    const int half = blockIdx.x & 1;
    const int b    = blockIdx.x >> 1;

    // ---- stage centered S as bf16: 8 threads per row k, 16 elems each ----
    {
        const int k = t >> 3, e8 = t & 7;
        const float4* srow = (const float4*)(s + k * L_SH + e8 * 16);
        float4 v[4];
        float sum = 0.0f;
        #pragma unroll
        for (int j = 0; j < 4; ++j) {
            v[j] = srow[j];
            sum += (v[j].x + v[j].y) + (v[j].z + v[j].w);
        }
        sum += __shfl_xor(sum, 1);
        sum += __shfl_xor(sum, 2);
        sum += __shfl_xor(sum, 4);
        const float mean = sum * (1.0f / 128.0f);
        uint4* dst = (uint4*)((char*)ldsS + k * (SSTR * 2) + e8 * 32);
        #pragma unroll
        for (int j = 0; j < 2; ++j) {
            uint4 o;
            o.x = pack2(f2bf(v[2*j].x - mean),   f2bf(v[2*j].y - mean));
            o.y = pack2(f2bf(v[2*j].z - mean),   f2bf(v[2*j].w - mean));
            o.z = pack2(f2bf(v[2*j+1].x - mean), f2bf(v[2*j+1].y - mean));
            o.w = pack2(f2bf(v[2*j+1].z - mean), f2bf(v[2*j+1].w - mean));
            dst[j] = o;
        }
        if (e8 == 7) *(uint4*)((char*)ldsS + k * (SSTR * 2) + 256) = make_uint4(0,0,0,0);
    }

    // ---- stage this half's x slice as 8 shifted bf16 copies ----
    {
        const float* __restrict__ xb = x + (size_t)b * T_LEN + half * 2048;
        const int navail = half ? 2048 : 2175;     // elems available in this slice
        const int a = t & 7;
        for (int i = (t >> 3); i < XSTRH / 8; i += 128) {   // 281 chunks
            const int p0 = 8 * i;
            float xv[16];
            if (p0 + 16 <= 2048) {
                const float4* sp = (const float4*)(xb + p0);
                #pragma unroll
                for (int j = 0; j < 4; ++j) *(float4*)(xv + 4 * j) = sp[j];
            } else {
                #pragma unroll
                for (int j = 0; j < 16; ++j) {
                    const int gi = p0 + j;
                    xv[j] = (gi < navail) ? xb[gi] : 0.0f;
                }
            }
            unsigned short bv[16];
            #pragma unroll
            for (int j = 0; j < 16; ++j) bv[j] = f2bf(xv[j]);
            uint4 o;
            o.x = pack2(bv[a],     bv[a + 1]);
            o.y = pack2(bv[a + 2], bv[a + 3]);
            o.z = pack2(bv[a + 4], bv[a + 5]);
            o.w = pack2(bv[a + 6], bv[a + 7]);
            *(uint4*)((char*)ldsX + a * (XSTRH * 2) + 2 * p0) = o;   // copy a elem p = x[p+a]
        }
    }
    __syncthreads();

    // ---- hoist B fragments (shapelets) to registers: 2 kts x 4 K-chunks ----
    bf16x8 bfr[2][4];
    #pragma unroll
    for (int kk = 0; kk < 2; ++kk)
        #pragma unroll
        for (int c = 0; c < 4; ++c)
            bfr[kk][c] = __builtin_bit_cast(bf16x8, *(const uint4*)(
                (const char*)ldsS + ((2 * wp + kk) * 16 + r) * (SSTR * 2) + 64 * c + 16 * q));

    // packed running top-5: elem0 -> ks = 32*wp + r, elem1 -> ks = 32*wp + 16 + r
    h2 rt[5];
    #pragma unroll
    for (int i = 0; i < 5; ++i) rt[i] = __builtin_bit_cast(h2, 0xFC00FC00u);  // (-inf,-inf)

    // group g starts at local tile g; advances 2 tiles (512 B) per step
    const char* xp = (const char*)ldsX + c7 * (XSTRH * 2) + 16 * q + 16 * ub + 32 * mtb
                   + g * 256;

#define TILE_STEP                                                               \
    {                                                                           \
        bf16x8 afr[10];                                                         \
        _Pragma("unroll")                                                       \
        for (int j = 0; j < 10; ++j)                                            \
            afr[j] = __builtin_bit_cast(bf16x8, *(const uint4*)(xp + 32 * j));  \
        xp += 512;                                                              \
        f32x4 acc0[4], acc1[4];                                                 \
        _Pragma("unroll")                                                       \
        for (int m = 0; m < 4; ++m) {                                           \
            acc0[m] = (f32x4){0.f, 0.f, 0.f, 0.f};                              \
            acc1[m] = (f32x4){0.f, 0.f, 0.f, 0.f};                              \
        }                                                                       \
        _Pragma("unroll")                                                       \
        for (int c = 0; c < 4; ++c) {                                           \
            _Pragma("unroll")                                                   \
            for (int m = 0; m < 4; ++m) {                                       \
                acc0[m] = __builtin_amdgcn_mfma_f32_16x16x32_bf16(afr[m + 2*c], bfr[0][c], acc0[m], 0, 0, 0); \
                acc1[m] = __builtin_amdgcn_mfma_f32_16x16x32_bf16(afr[m + 2*c], bfr[1][c], acc1[m], 0, 0, 0); \
            }                                                                   \
        }                                                                       \
        select32(acc0, acc1, rt);                                               \
    }

    // local tiles: half0 g0: {0,2,..,14}, g1: {1,..,15}; half1 g0: {0,..,14},
    // g1: {1,..,13} (lt=15 would start n=3968 -> handled as boundary row).
    for (int st = 0; st < 7; ++st) { TILE_STEP }
    if (!(half & g)) { TILE_STEP }
#undef TILE_STEP

    // ---- boundary row n = 3968 (upper half, local elem 1920) ----
    if (half == 1 && g == 1 && mh == 0) {
        f32x4 e0 = (f32x4){0.f, 0.f, 0.f, 0.f};
        f32x4 e1 = (f32x4){0.f, 0.f, 0.f, 0.f};
        const char* eb = (const char*)ldsX + c7 * (XSTRH * 2) + 3840 + 16 * q + 16 * ub;
        #pragma unroll
        for (int c = 0; c < 4; ++c) {
            const bf16x8 af = __builtin_bit_cast(bf16x8, *(const uint4*)(eb + 64 * c));
            e0 = __builtin_amdgcn_mfma_f32_16x16x32_bf16(af, bfr[0][c], e0, 0, 0, 0);
            e1 = __builtin_amdgcn_mfma_f32_16x16x32_bf16(af, bfr[1][c], e1, 0, 0, 0);
        }
        if (q == 0) insert1_2(cvt2(e0[0], e1[0]), rt);   // n = 3968 for both lists
    }

    // ---- butterfly merge across quads (snapshot BEFORE merging) ----
    #pragma unroll
    for (int mask = 16; mask <= 32; mask <<= 1) {
        h2 sv[5];
        #pragma unroll
        for (int i = 0; i < 5; ++i)
            sv[i] = __builtin_bit_cast(h2, __shfl_xor(__builtin_bit_cast(int, rt[i]), mask));
        merge55_2(rt[0], rt[1], rt[2], rt[3], rt[4], sv[0], sv[1], sv[2], sv[3], sv[4]);
    }

    // ---- cross-(g, mh) merge via LDS: 3 writer combos, reader (g=0, mh=0) ----
    __syncthreads();   // bfr-hoist reads of ldsS long done; reuse as scratch
    unsigned int* pbuf = (unsigned int*)ldsS;   // [region][wp*16 + r][5]
    if ((g != 0 || mh != 0) && q == 0) {
        const int reg = (g * 2 + mh) - 1;       // 0..2
        unsigned int* p = pbuf + ((reg * 64) + wp * 16 + r) * 5;
        #pragma unroll
        for (int i = 0; i < 5; ++i) p[i] = __builtin_bit_cast(unsigned int, rt[i]);
    }
    __syncthreads();
    if (g == 0 && mh == 0 && q == 0) {
        #pragma unroll
        for (int reg = 0; reg < 3; ++reg) {
            const unsigned int* p = pbuf + ((reg * 64) + wp * 16 + r) * 5;
            h2 sv[5];
            #pragma unroll
            for (int i = 0; i < 5; ++i) sv[i] = __builtin_bit_cast(h2, p[i]);
            merge55_2(rt[0], rt[1], rt[2], rt[3], rt[4], sv[0], sv[1], sv[2], sv[3], sv[4]);
        }
        // packed partials: part[(half*5 + j)*16384 + b*64 + cid]
        const int cid = wp * 16 + r;
        unsigned int* p = part + (size_t)(half * 5) * 16384 + b * 64 + cid;
        #pragma unroll
        for (int j = 0; j < 5; ++j)
            p[(size_t)j * 16384] = __builtin_bit_cast(unsigned int, rt[j]);
    }
}

// Kernel 2: merge the two half partials per (b, cid), emit features for 2 ks each
__global__ void merge_half_kernel(const unsigned int* __restrict__ part,
                                  float* __restrict__ out) {
    const int gid = blockIdx.x * 256 + threadIdx.x;   // 0 .. 16383
    const int b   = gid >> 6;
    const int cid = gid & 63;

    h2 rt[5], sv[5];
    #pragma unroll
    for (int j = 0; j < 5; ++j) rt[j] = __builtin_bit_cast(h2, part[(size_t)j * 16384 + gid]);
    #pragma unroll
    for (int j = 0; j < 5; ++j) sv[j] = __builtin_bit_cast(h2, part[(size_t)(5 + j) * 16384 + gid]);
    merge55_2(rt[0], rt[1], rt[2], rt[3], rt[4], sv[0], sv[1], sv[2], sv[3], sv[4]);

    const float A0 = (float)rt[0][0], A1 = (float)rt[1][0], A2 = (float)rt[2][0],
                A3 = (float)rt[3][0], A4 = (float)rt[4][0];
    const float B0 = (float)rt[0][1], B1 = (float)rt[1][1], B2 = (float)rt[2][1],
                B3 = (float)rt[3][1], B4 = (float)rt[4][1];
    float* ob = out + (size_t)b * (4 * K_SH);
    const int ksA = 32 * (cid >> 4) + (cid & 15), ksB = ksA + 16;
    const float mA = (((A0 + A1) + (A2 + A3)) + A4) * 0.2f;
    const float mB = (((B0 + B1) + (B2 + B3)) + B4) * 0.2f;
    ob[ksA]           = A0;
    ob[K_SH + ksA]    = mA;
    ob[2*K_SH + ksA]  = A1;
    ob[3*K_SH + ksA]  = fmaxf(A0 - A1, 0.0f);
    ob[ksB]           = B0;
    ob[K_SH + ksB]    = mB;
    ob[2*K_SH + ksB]  = B1;
    ob[3*K_SH + ksB]  = fmaxf(B0 - B1, 0.0f);
}

extern "C" void kernel_launch(void* const* d_in, const int* in_sizes, int n_in,
                              void* d_out, int out_size, void* d_ws, size_t ws_size,
                              hipStream_t stream) {
    const float* x = (const float*)d_in[0];        // (256, 4096) fp32
    const float* s = (const float*)d_in[1];        // (128, 128)  fp32
    float* out = (float*)d_out;                    // (256, 512)  fp32
    unsigned int* part = (unsigned int*)d_ws;      // 10 * 16384 u32 = 640 KB

    shapelet_half_kernel<<<2 * B_SZ, 1024, 0, stream>>>(x, s, part);
    merge_half_kernel<<<64, 256, 0, stream>>>(part, out);
}